// Round 2
// baseline (14190.672 us; speedup 1.0000x reference)
//
#include <hip/hip_runtime.h>
#include <hip/hip_bf16.h>

// LSTM: T=512, B=64, H=512, L=2.  inputs: x[T,B,H] f32, Wh[L,H,4H], Wx[L,H,4H], bh[L,4H]
// out = concat(out[T,B,H], h_fin[L,B,H], c_fin[L,B,H]) f32.
//
// Persistent-kernel design: 64 WGs (layer = wg>>5, strip = wg&31), 513 pipelined
// stages (layer0 @ t=s, layer1 @ t=s-1) separated by a device-scope flag barrier.
// c lives in registers for the whole sequence; h ping-pongs through global bf16.

#define TSEQ 512
#define BATCH 64
#define HID 512
#define H4 2048
#define BH (BATCH * HID)
#define NWG 64

typedef short bf16x8 __attribute__((ext_vector_type(8)));
typedef float f32x4 __attribute__((ext_vector_type(4)));

__device__ __forceinline__ ushort f32_to_bf16(float f) {
    unsigned u = __builtin_bit_cast(unsigned, f);
    u += 0x7FFFu + ((u >> 16) & 1u);   // round-to-nearest-even
    return (ushort)(u >> 16);
}

// ---- convert x f32 -> bf16 (vectorized) ----
__global__ __launch_bounds__(256) void convert_x(const float* __restrict__ x,
                                                 ushort* __restrict__ xq) {
    const int n4 = (TSEQ * BATCH * HID) / 4;
    int stride = gridDim.x * blockDim.x;
    for (int i = blockIdx.x * blockDim.x + threadIdx.x; i < n4; i += stride) {
        float4 v = ((const float4*)x)[i];
        ushort4 o;
        o.x = f32_to_bf16(v.x);
        o.y = f32_to_bf16(v.y);
        o.z = f32_to_bf16(v.z);
        o.w = f32_to_bf16(v.w);
        ((ushort4*)xq)[i] = o;
    }
}

// ---- transpose+convert weights: WT[m][n][k] = W[k][n], m: 0=Wx0 1=Wh0 2=Wx1 3=Wh1 ----
__global__ __launch_bounds__(256) void transpose_w(const float* __restrict__ Wh,
                                                   const float* __restrict__ Wx,
                                                   ushort* __restrict__ WT) {
    int bid = blockIdx.x;            // 4 * 8 * 32 = 1024 blocks
    int m  = bid >> 8;               // 0..3
    int kt = (bid >> 5) & 7;         // k tile (64)
    int nt = bid & 31;               // n tile (64)
    const float* src = ((m & 1) ? Wh : Wx) + (size_t)(m >> 1) * (HID * H4);

    __shared__ float tile[64][65];
    int c  = threadIdx.x & 63;
    int r0 = (threadIdx.x >> 6) * 16;
    for (int i = 0; i < 16; ++i) {
        int r = r0 + i;
        tile[r][c] = src[(size_t)(kt * 64 + r) * H4 + nt * 64 + c];
    }
    __syncthreads();
    int k  = threadIdx.x & 63;
    int n0 = (threadIdx.x >> 6) * 16;
    for (int i = 0; i < 16; ++i) {
        int n = n0 + i;
        WT[(size_t)m * (H4 * HID) + (size_t)(nt * 64 + n) * HID + kt * 64 + k] =
            f32_to_bf16(tile[k][n]);
    }
}

// ---- persistent LSTM kernel ----
__global__ __launch_bounds__(256, 1) void lstm_persistent(
    const ushort* __restrict__ WT,   // [4][2048][512] bf16 (N-major, K contiguous)
    const ushort* __restrict__ xq,   // [512][64][512] bf16
    const float*  __restrict__ bh,   // [2][2048]
    ushort* __restrict__ h0q,        // [2][64][512] bf16 ping-pong
    ushort* __restrict__ h1q,        // [2][64][512]
    float*  __restrict__ out,        // d_out
    int*    __restrict__ flags)      // [64] stage counters, zeroed before launch
{
    const int w     = blockIdx.x;    // 0..63
    const int layer = w >> 5;
    const int strip = w & 31;
    const int j0    = strip * 16;
    const int wave  = threadIdx.x >> 6;   // gate 0..3 (i,f,g,o)
    const int lane  = threadIdx.x & 63;
    const int lo    = lane & 15;
    const int hi    = lane >> 4;

    // stage-invariant weight fragment pointers (gemm_bt layout, k contiguous-8/lane)
    const ushort* B1 = WT + (size_t)(layer * 2 + 0) * (H4 * HID);   // Wx^T
    const ushort* B2 = WT + (size_t)(layer * 2 + 1) * (H4 * HID);   // Wh^T
    const ushort* b1p = B1 + (size_t)(512 * wave + j0 + lo) * HID + hi * 8;
    const ushort* b2p = B2 + (size_t)(512 * wave + j0 + lo) * HID + hi * 8;
    const float bias = bh[layer * H4 + 512 * wave + j0 + lo];

    // cell state in registers: cell = threadIdx.x + q*256 -> b = cell>>4, c = cell&15
    float creg[4] = {0.f, 0.f, 0.f, 0.f};

    __shared__ float lds_g[4][64][16];

    for (int s = 0; s <= TSEQ; ++s) {
        // ---- barrier: wait for all WGs to have finished stage s-1 ----
        if (s > 0) {
            if (threadIdx.x < NWG) {
                while (__hip_atomic_load(&flags[threadIdx.x], __ATOMIC_ACQUIRE,
                                         __HIP_MEMORY_SCOPE_AGENT) < s) { /* spin */ }
            }
            __syncthreads();
        }

        const int t = s - layer;
        if (t >= 0 && t < TSEQ) {    // uniform per-WG condition
            const ushort *A1, *A2;
            if (layer == 0) {
                A1 = xq  + (size_t)t * BH;
                A2 = h0q + (size_t)((t + 1) & 1) * BH;   // h0[t-1]
            } else {
                A1 = h0q + (size_t)(t & 1) * BH;         // h0[t]
                A2 = h1q + (size_t)((t + 1) & 1) * BH;   // h1[t-1]
            }
            const ushort* a1p = A1 + (size_t)lo * HID + hi * 8;
            const ushort* a2p = A2 + (size_t)lo * HID + hi * 8;

            f32x4 acc[4] = {(f32x4)(0.f), (f32x4)(0.f), (f32x4)(0.f), (f32x4)(0.f)};
#pragma unroll
            for (int kk = 0; kk < 16; ++kk) {
                bf16x8 b1 = *(const bf16x8*)(b1p + kk * 32);
                bf16x8 b2 = *(const bf16x8*)(b2p + kk * 32);
#pragma unroll
                for (int mt = 0; mt < 4; ++mt) {
                    bf16x8 a1 = *(const bf16x8*)(a1p + mt * 16 * HID + kk * 32);
                    acc[mt] = __builtin_amdgcn_mfma_f32_16x16x32_bf16(a1, b1, acc[mt], 0, 0, 0);
                    bf16x8 a2 = *(const bf16x8*)(a2p + mt * 16 * HID + kk * 32);
                    acc[mt] = __builtin_amdgcn_mfma_f32_16x16x32_bf16(a2, b2, acc[mt], 0, 0, 0);
                }
            }

            // gate tiles -> LDS (C/D layout: col = lane&15, row = (lane>>4)*4 + reg)
            float bb = bias;
#pragma unroll
            for (int mt = 0; mt < 4; ++mt)
#pragma unroll
                for (int r = 0; r < 4; ++r)
                    lds_g[wave][mt * 16 + hi * 4 + r][lo] = acc[mt][r] + bb;
            __syncthreads();

            ushort* hq = ((layer == 0) ? h0q : h1q) + (size_t)(t & 1) * BH;
#pragma unroll
            for (int q = 0; q < 4; ++q) {
                int cell = threadIdx.x + q * 256;    // 0..1023
                int b = cell >> 4;
                int c = cell & 15;
                float iv = lds_g[0][b][c];
                float fv = lds_g[1][b][c];
                float gv = lds_g[2][b][c];
                float ov = lds_g[3][b][c];
                float si = 1.f / (1.f + __expf(-iv));
                float sf = 1.f / (1.f + __expf(-fv));
                float so = 1.f / (1.f + __expf(-ov));
                float tg = tanhf(gv);
                float cn = sf * creg[q] + si * tg;
                float hn = so * tanhf(cn);
                creg[q] = cn;
                size_t gidx = (size_t)b * HID + j0 + c;
                hq[gidx] = f32_to_bf16(hn);
                if (layer == 1)
                    out[(size_t)t * BH + gidx] = hn;
                if (t == TSEQ - 1) {
                    size_t base = (size_t)TSEQ * BH;
                    out[base + (size_t)layer * BH + gidx] = hn;                    // h_fin
                    out[base + (size_t)2 * BH + (size_t)layer * BH + gidx] = cn;   // c_fin
                }
            }
        }

        // ---- publish: make h-slice agent-visible, then bump our flag ----
        __threadfence();      // each thread: stores complete + L2 writeback (agent scope)
        __syncthreads();      // whole WG done publishing
        if (threadIdx.x == 0)
            __hip_atomic_store(&flags[w], s + 1, __ATOMIC_RELEASE,
                               __HIP_MEMORY_SCOPE_AGENT);
    }
}

extern "C" void kernel_launch(void* const* d_in, const int* in_sizes, int n_in,
                              void* d_out, int out_size, void* d_ws, size_t ws_size,
                              hipStream_t stream) {
    const float* x  = (const float*)d_in[0];
    const float* Wh = (const float*)d_in[1];
    const float* Wx = (const float*)d_in[2];
    const float* bh = (const float*)d_in[3];
    float* out = (float*)d_out;

    char* ws = (char*)d_ws;
    // layout: WT 8MB | xq 32MB | h0q/h1q 256KB | flags
    ushort* WT = (ushort*)ws;
    ushort* xq = (ushort*)(ws + ((size_t)8 << 20));
    char* state = ws + ((size_t)8 << 20) + ((size_t)32 << 20);
    ushort* h0q = (ushort*)state;                  // [2][64][512] bf16
    ushort* h1q = h0q + 2 * BH;                    // [2][64][512] bf16
    int* flags  = (int*)(h1q + 2 * BH);            // [64]
    size_t clear_bytes = (size_t)4 * BH * sizeof(ushort) + NWG * sizeof(int);

    hipMemsetAsync(state, 0, clear_bytes, stream); // zero h state + flags (every launch)
    convert_x<<<2048, 256, 0, stream>>>(x, xq);
    transpose_w<<<1024, 256, 0, stream>>>(Wh, Wx, WT);
    lstm_persistent<<<NWG, 256, 0, stream>>>(WT, xq, bh, h0q, h1q, out, flags);
}

// Round 3
// 8634.185 us; speedup vs baseline: 1.6435x; 1.6435x over previous
//
#include <hip/hip_runtime.h>
#include <hip/hip_bf16.h>

// LSTM: T=512, B=64, H=512, L=2.  inputs: x[T,B,H] f32, Wh[L,H,4H], Wx[L,H,4H], bh[L,4H]
// out = concat(out[T,B,H], h_fin[L,B,H], c_fin[L,B,H]) f32.
//
// Persistent kernel, 64 WGs (layer = wg>>5, strip = wg&31), flag-synchronized
// pipelined stages. Key fix vs R2: relaxed-spin + ONE acquire fence per stage
// (R2's acquire-per-poll emitted buffer_inv per iteration, nuking L2 weights).
// h rings are DEPTH=4 + a permanently-zero slot; layer0 waits for layer1 with
// 2-stage slack only (anti-dependency on ring reuse).

#define TSEQ 512
#define BATCH 64
#define HID 512
#define H4 2048
#define BH (BATCH * HID)
#define DEPTH 4
#define ZSLOT DEPTH

typedef short bf16x8 __attribute__((ext_vector_type(8)));
typedef float f32x4 __attribute__((ext_vector_type(4)));
typedef unsigned long long u64;

__device__ __forceinline__ ushort f32_to_bf16(float f) {
    unsigned u = __builtin_bit_cast(unsigned, f);
    u += 0x7FFFu + ((u >> 16) & 1u);   // round-to-nearest-even
    return (ushort)(u >> 16);
}

// ---- convert x f32 -> bf16 (vectorized) ----
__global__ __launch_bounds__(256) void convert_x(const float* __restrict__ x,
                                                 ushort* __restrict__ xq) {
    const int n4 = (TSEQ * BATCH * HID) / 4;
    int stride = gridDim.x * blockDim.x;
    for (int i = blockIdx.x * blockDim.x + threadIdx.x; i < n4; i += stride) {
        float4 v = ((const float4*)x)[i];
        ushort4 o;
        o.x = f32_to_bf16(v.x);
        o.y = f32_to_bf16(v.y);
        o.z = f32_to_bf16(v.z);
        o.w = f32_to_bf16(v.w);
        ((ushort4*)xq)[i] = o;
    }
}

// ---- transpose+convert weights: WT[m][n][k] = W[k][n], m: 0=Wx0 1=Wh0 2=Wx1 3=Wh1 ----
__global__ __launch_bounds__(256) void transpose_w(const float* __restrict__ Wh,
                                                   const float* __restrict__ Wx,
                                                   ushort* __restrict__ WT) {
    int bid = blockIdx.x;            // 4 * 8 * 32 = 1024 blocks
    int m  = bid >> 8;               // 0..3
    int kt = (bid >> 5) & 7;         // k tile (64)
    int nt = bid & 31;               // n tile (64)
    const float* src = ((m & 1) ? Wh : Wx) + (size_t)(m >> 1) * (HID * H4);

    __shared__ float tile[64][65];
    int c  = threadIdx.x & 63;
    int r0 = (threadIdx.x >> 6) * 16;
    for (int i = 0; i < 16; ++i) {
        int r = r0 + i;
        tile[r][c] = src[(size_t)(kt * 64 + r) * H4 + nt * 64 + c];
    }
    __syncthreads();
    int k  = threadIdx.x & 63;
    int n0 = (threadIdx.x >> 6) * 16;
    for (int i = 0; i < 16; ++i) {
        int n = n0 + i;
        WT[(size_t)m * (H4 * HID) + (size_t)(nt * 64 + n) * HID + kt * 64 + k] =
            f32_to_bf16(tile[k][n]);
    }
}

// ---- persistent LSTM kernel ----
__global__ __launch_bounds__(256, 1) void lstm_persistent(
    const ushort* __restrict__ WT,   // [4][2048][512] bf16 (N-major, K contiguous)
    const ushort* __restrict__ xq,   // [512][64][512] bf16
    const float*  __restrict__ bh,   // [2][2048]
    ushort* __restrict__ h0r,        // [DEPTH+1][64][512] bf16 ring (+ zero slot)
    ushort* __restrict__ h1r,        // [DEPTH+1][64][512]
    float*  __restrict__ out,        // d_out
    int*    __restrict__ flagsL0,    // [32]
    int*    __restrict__ flagsL1)    // [32]
{
    const int w     = blockIdx.x;    // 0..63
    const int layer = w >> 5;
    const int strip = w & 31;
    const int j0    = strip * 16;
    const int tid   = threadIdx.x;
    const int wv    = tid >> 6;      // wave 0..3
    const int lane  = tid & 63;
    const int rh    = wv >> 1;       // row-half (32 batch rows)
    const int gh    = wv & 1;        // gate-pair half
    const int lo    = lane & 15;
    const int hi    = lane >> 4;

    // B fragment pointers (gemm_bt layout, k contiguous-8/lane)
    const ushort* B1 = WT + (size_t)(layer * 2 + 0) * (H4 * HID);   // Wx^T
    const ushort* B2 = WT + (size_t)(layer * 2 + 1) * (H4 * HID);   // Wh^T
    const ushort* b1p0 = B1 + (size_t)(512 * (gh * 2 + 0) + j0 + lo) * HID + hi * 8;
    const ushort* b1p1 = B1 + (size_t)(512 * (gh * 2 + 1) + j0 + lo) * HID + hi * 8;
    const ushort* b2p0 = B2 + (size_t)(512 * (gh * 2 + 0) + j0 + lo) * HID + hi * 8;
    const ushort* b2p1 = B2 + (size_t)(512 * (gh * 2 + 1) + j0 + lo) * HID + hi * 8;

    // A fragment element offsets (rows rh*32 + mt*16 + lo, k = hi*8 + kk*32)
    const int aoff0 = (rh * 32 + lo) * HID + hi * 8;
    const int aoff1 = aoff0 + 16 * HID;

    // pin Wh fragments in registers for the whole sequence (32 x bf16x8 = 128 VGPR)
    bf16x8 wh[32];
#pragma unroll
    for (int kk = 0; kk < 16; ++kk) {
        wh[kk * 2 + 0] = *(const bf16x8*)(b2p0 + kk * 32);
        wh[kk * 2 + 1] = *(const bf16x8*)(b2p1 + kk * 32);
    }

    // gate-stage cell mapping: 4 consecutive cells per thread
    const int brow = tid >> 2;          // batch row 0..63
    const int c0   = (tid & 3) * 4;     // col offset within 16-wide strip
    f32x4 bias4[4];
#pragma unroll
    for (int g = 0; g < 4; ++g)
        bias4[g] = *(const f32x4*)&bh[layer * H4 + 512 * g + j0 + c0];

    f32x4 creg = (f32x4)(0.f);          // cell state, cells tid*4 .. tid*4+3

    __shared__ float lds_g[4][64][16];

    for (int s = 0; s <= TSEQ; ++s) {
        // ---- stage barrier: relaxed spin, then ONE acquire fence ----
        if (s > 0) {
            if (tid < 64) {
                const int* f  = (tid < 32) ? &flagsL0[tid] : &flagsL1[tid - 32];
                const int thr = (tid < 32) ? s : (layer == 0 ? s - 2 : s);
                while (__hip_atomic_load(f, __ATOMIC_RELAXED,
                                         __HIP_MEMORY_SCOPE_AGENT) < thr) { }
            }
            __syncthreads();
            __builtin_amdgcn_fence(__ATOMIC_ACQUIRE, "agent");   // one buffer_inv/stage
        }

        const int t = s - layer;
        if (t >= 0 && t < TSEQ) {
            const int pslot = (t == 0) ? ZSLOT : ((t - 1) & (DEPTH - 1));
            const ushort* A1;
            const ushort* A2;
            if (layer == 0) {
                A1 = xq  + (size_t)t * BH;
                A2 = h0r + (size_t)pslot * BH;
            } else {
                A1 = h0r + (size_t)(t & (DEPTH - 1)) * BH;
                A2 = h1r + (size_t)pslot * BH;
            }

            f32x4 acc[2][2];
#pragma unroll
            for (int mt = 0; mt < 2; ++mt)
#pragma unroll
                for (int gs = 0; gs < 2; ++gs)
                    acc[mt][gs] = (f32x4)(0.f);

#pragma unroll
            for (int kk = 0; kk < 16; ++kk) {
                const int ko = kk * 32;
                bf16x8 a10 = *(const bf16x8*)(A1 + aoff0 + ko);
                bf16x8 a11 = *(const bf16x8*)(A1 + aoff1 + ko);
                bf16x8 a20 = *(const bf16x8*)(A2 + aoff0 + ko);
                bf16x8 a21 = *(const bf16x8*)(A2 + aoff1 + ko);
                bf16x8 q10 = *(const bf16x8*)(b1p0 + ko);
                bf16x8 q11 = *(const bf16x8*)(b1p1 + ko);
                acc[0][0] = __builtin_amdgcn_mfma_f32_16x16x32_bf16(a10, q10, acc[0][0], 0, 0, 0);
                acc[0][0] = __builtin_amdgcn_mfma_f32_16x16x32_bf16(a20, wh[kk * 2 + 0], acc[0][0], 0, 0, 0);
                acc[0][1] = __builtin_amdgcn_mfma_f32_16x16x32_bf16(a10, q11, acc[0][1], 0, 0, 0);
                acc[0][1] = __builtin_amdgcn_mfma_f32_16x16x32_bf16(a20, wh[kk * 2 + 1], acc[0][1], 0, 0, 0);
                acc[1][0] = __builtin_amdgcn_mfma_f32_16x16x32_bf16(a11, q10, acc[1][0], 0, 0, 0);
                acc[1][0] = __builtin_amdgcn_mfma_f32_16x16x32_bf16(a21, wh[kk * 2 + 0], acc[1][0], 0, 0, 0);
                acc[1][1] = __builtin_amdgcn_mfma_f32_16x16x32_bf16(a11, q11, acc[1][1], 0, 0, 0);
                acc[1][1] = __builtin_amdgcn_mfma_f32_16x16x32_bf16(a21, wh[kk * 2 + 1], acc[1][1], 0, 0, 0);
            }

            // gate tiles -> LDS (C/D layout: col = lane&15, row = (lane>>4)*4 + reg)
#pragma unroll
            for (int mt = 0; mt < 2; ++mt)
#pragma unroll
                for (int gs = 0; gs < 2; ++gs)
#pragma unroll
                    for (int r = 0; r < 4; ++r)
                        lds_g[gh * 2 + gs][rh * 32 + mt * 16 + hi * 4 + r][lo] = acc[mt][gs][r];
            __syncthreads();

            // gates: each thread handles 4 consecutive cells of row brow
            f32x4 gi = *(const f32x4*)&lds_g[0][brow][c0] + bias4[0];
            f32x4 gf = *(const f32x4*)&lds_g[1][brow][c0] + bias4[1];
            f32x4 gg = *(const f32x4*)&lds_g[2][brow][c0] + bias4[2];
            f32x4 go = *(const f32x4*)&lds_g[3][brow][c0] + bias4[3];
            f32x4 cn, hn;
#pragma unroll
            for (int q = 0; q < 4; ++q) {
                float si = 1.f / (1.f + __expf(-gi[q]));
                float sf = 1.f / (1.f + __expf(-gf[q]));
                float so = 1.f / (1.f + __expf(-go[q]));
                float tg = tanhf(gg[q]);
                cn[q] = sf * creg[q] + si * tg;
                hn[q] = so * tanhf(cn[q]);
            }
            creg = cn;

            // publish h (normal cached store; release fence below pushes it out)
            ushort* hw = ((layer == 0) ? h0r : h1r)
                       + (size_t)(t & (DEPTH - 1)) * BH + (size_t)brow * HID + j0 + c0;
            u64 hp = (u64)f32_to_bf16(hn[0])
                   | ((u64)f32_to_bf16(hn[1]) << 16)
                   | ((u64)f32_to_bf16(hn[2]) << 32)
                   | ((u64)f32_to_bf16(hn[3]) << 48);
            *(u64*)hw = hp;

            if (layer == 1)
                *(f32x4*)&out[(size_t)t * BH + (size_t)brow * HID + j0 + c0] = hn;
            if (t == TSEQ - 1) {
                size_t base = (size_t)TSEQ * BH + (size_t)layer * BH
                            + (size_t)brow * HID + j0 + c0;
                *(f32x4*)&out[base] = hn;                       // h_fin
                *(f32x4*)&out[base + 2 * (size_t)BH] = cn;      // c_fin
            }
        }

        // ---- publish flag: drain own stores, then one release store ----
        asm volatile("s_waitcnt vmcnt(0)" ::: "memory");
        __syncthreads();
        if (tid == 0)
            __hip_atomic_store(layer ? &flagsL1[strip] : &flagsL0[strip], s + 1,
                               __ATOMIC_RELEASE, __HIP_MEMORY_SCOPE_AGENT);
    }
}

extern "C" void kernel_launch(void* const* d_in, const int* in_sizes, int n_in,
                              void* d_out, int out_size, void* d_ws, size_t ws_size,
                              hipStream_t stream) {
    const float* x  = (const float*)d_in[0];
    const float* Wh = (const float*)d_in[1];
    const float* Wx = (const float*)d_in[2];
    const float* bh = (const float*)d_in[3];
    float* out = (float*)d_out;

    char* ws = (char*)d_ws;
    // layout: WT 8MB | xq 32MB | h0r | h1r | flags   (~40.6MB total)
    ushort* WT = (ushort*)ws;
    ushort* xq = (ushort*)(ws + ((size_t)8 << 20));
    char* state = ws + ((size_t)8 << 20) + ((size_t)32 << 20);
    ushort* h0r = (ushort*)state;                          // [DEPTH+1][64][512]
    ushort* h1r = h0r + (size_t)(DEPTH + 1) * BH;
    int* flagsL0 = (int*)(h1r + (size_t)(DEPTH + 1) * BH); // [32]
    int* flagsL1 = flagsL0 + 32;
    size_t clear_bytes = (size_t)2 * (DEPTH + 1) * BH * sizeof(ushort) + 64 * sizeof(int);

    hipMemsetAsync(state, 0, clear_bytes, stream);  // zero rings + zero-slots + flags
    convert_x<<<2048, 256, 0, stream>>>(x, xq);
    transpose_w<<<1024, 256, 0, stream>>>(Wh, Wx, WT);
    lstm_persistent<<<64, 256, 0, stream>>>(WT, xq, bh, h0r, h1r, out, flagsL0, flagsL1);
}

// Round 4
// 8546.296 us; speedup vs baseline: 1.6604x; 1.0103x over previous
//
#include <hip/hip_runtime.h>
#include <hip/hip_bf16.h>

// LSTM: T=512, B=64, H=512, L=2.  inputs: x[T,B,H] f32, Wh[L,H,4H], Wx[L,H,4H], bh[L,4H]
// out = concat(out[T,B,H], h_fin[L,B,H], c_fin[L,B,H]) f32.
//
// Persistent kernel, 64 WGs (layer = wg>>5, strip = wg&31), flag-synchronized
// pipelined stages. R4 key change: NO agent fences anywhere (R3's acquire fence
// = buffer_inv and release store = buffer_wbl2, executed 64x/stage, flushed all
// per-XCD L2s every stage -> 400MB refetch + ~10us/stage latency). Instead all
// cross-WG data (h rings, flags) moves via relaxed agent-scope atomics, which
// lower to sc1 loads/stores: coherent at the MALL, bypassing L2. Weights/xq
// stay normal cached loads and remain L2-resident across all stages. Per-wave
// in-order VMEM issue + s_waitcnt vmcnt(0) gives flag-after-data ordering.

#define TSEQ 512
#define BATCH 64
#define HID 512
#define H4 2048
#define BH (BATCH * HID)
#define DEPTH 8
#define ZSLOT DEPTH

typedef short bf16x8 __attribute__((ext_vector_type(8)));
typedef float f32x4 __attribute__((ext_vector_type(4)));
typedef unsigned long long u64;

__device__ __forceinline__ ushort f32_to_bf16(float f) {
    unsigned u = __builtin_bit_cast(unsigned, f);
    u += 0x7FFFu + ((u >> 16) & 1u);   // round-to-nearest-even
    return (ushort)(u >> 16);
}

// coherent (agent-scope, sc1) 16B h-fragment load: bypasses L1/L2, reads MALL
__device__ __forceinline__ bf16x8 load_h8(const ushort* p) {
    u64 lo = __hip_atomic_load((const u64*)p, __ATOMIC_RELAXED, __HIP_MEMORY_SCOPE_AGENT);
    u64 hi = __hip_atomic_load(((const u64*)p) + 1, __ATOMIC_RELAXED, __HIP_MEMORY_SCOPE_AGENT);
    union { u64 q[2]; bf16x8 v; } u;
    u.q[0] = lo; u.q[1] = hi;
    return u.v;
}

// ---- convert x f32 -> bf16 (vectorized) ----
__global__ __launch_bounds__(256) void convert_x(const float* __restrict__ x,
                                                 ushort* __restrict__ xq) {
    const int n4 = (TSEQ * BATCH * HID) / 4;
    int stride = gridDim.x * blockDim.x;
    for (int i = blockIdx.x * blockDim.x + threadIdx.x; i < n4; i += stride) {
        float4 v = ((const float4*)x)[i];
        ushort4 o;
        o.x = f32_to_bf16(v.x);
        o.y = f32_to_bf16(v.y);
        o.z = f32_to_bf16(v.z);
        o.w = f32_to_bf16(v.w);
        ((ushort4*)xq)[i] = o;
    }
}

// ---- transpose+convert weights: WT[m][n][k] = W[k][n], m: 0=Wx0 1=Wh0 2=Wx1 3=Wh1 ----
__global__ __launch_bounds__(256) void transpose_w(const float* __restrict__ Wh,
                                                   const float* __restrict__ Wx,
                                                   ushort* __restrict__ WT) {
    int bid = blockIdx.x;            // 4 * 8 * 32 = 1024 blocks
    int m  = bid >> 8;               // 0..3
    int kt = (bid >> 5) & 7;         // k tile (64)
    int nt = bid & 31;               // n tile (64)
    const float* src = ((m & 1) ? Wh : Wx) + (size_t)(m >> 1) * (HID * H4);

    __shared__ float tile[64][65];
    int c  = threadIdx.x & 63;
    int r0 = (threadIdx.x >> 6) * 16;
    for (int i = 0; i < 16; ++i) {
        int r = r0 + i;
        tile[r][c] = src[(size_t)(kt * 64 + r) * H4 + nt * 64 + c];
    }
    __syncthreads();
    int k  = threadIdx.x & 63;
    int n0 = (threadIdx.x >> 6) * 16;
    for (int i = 0; i < 16; ++i) {
        int n = n0 + i;
        WT[(size_t)m * (H4 * HID) + (size_t)(nt * 64 + n) * HID + kt * 64 + k] =
            f32_to_bf16(tile[k][n]);
    }
}

// ---- persistent LSTM kernel ----
__global__ __launch_bounds__(256, 1) void lstm_persistent(
    const ushort* __restrict__ WT,   // [4][2048][512] bf16 (N-major, K contiguous)
    const ushort* __restrict__ xq,   // [512][64][512] bf16
    const float*  __restrict__ bh,   // [2][2048]
    ushort* __restrict__ h0r,        // [DEPTH+1][64][512] bf16 ring (+ zero slot)
    ushort* __restrict__ h1r,        // [DEPTH+1][64][512]
    float*  __restrict__ out,        // d_out
    int*    __restrict__ flagsL0,    // [32]
    int*    __restrict__ flagsL1)    // [32]
{
    const int w     = blockIdx.x;    // 0..63
    const int layer = w >> 5;
    const int strip = w & 31;
    const int j0    = strip * 16;
    const int tid   = threadIdx.x;
    const int wv    = tid >> 6;      // wave 0..3
    const int lane  = tid & 63;
    const int rh    = wv >> 1;       // row-half (32 batch rows)
    const int gh    = wv & 1;        // gate-pair half
    const int lo    = lane & 15;
    const int hi    = lane >> 4;

    // B fragment pointers (gemm_bt layout, k contiguous-8/lane)
    const ushort* B1 = WT + (size_t)(layer * 2 + 0) * (H4 * HID);   // Wx^T
    const ushort* B2 = WT + (size_t)(layer * 2 + 1) * (H4 * HID);   // Wh^T
    const ushort* b1p0 = B1 + (size_t)(512 * (gh * 2 + 0) + j0 + lo) * HID + hi * 8;
    const ushort* b1p1 = B1 + (size_t)(512 * (gh * 2 + 1) + j0 + lo) * HID + hi * 8;
    const ushort* b2p0 = B2 + (size_t)(512 * (gh * 2 + 0) + j0 + lo) * HID + hi * 8;
    const ushort* b2p1 = B2 + (size_t)(512 * (gh * 2 + 1) + j0 + lo) * HID + hi * 8;

    // pin BOTH weight matrices' fragments in registers for the whole sequence
    // (2 x 32 x bf16x8 = 256 VGPR; 1 wave/SIMD so up to 512 available)
    bf16x8 wx[32], wh[32];
#pragma unroll
    for (int kk = 0; kk < 16; ++kk) {
        wx[kk * 2 + 0] = *(const bf16x8*)(b1p0 + kk * 32);
        wx[kk * 2 + 1] = *(const bf16x8*)(b1p1 + kk * 32);
        wh[kk * 2 + 0] = *(const bf16x8*)(b2p0 + kk * 32);
        wh[kk * 2 + 1] = *(const bf16x8*)(b2p1 + kk * 32);
    }

    // A fragment element offsets (rows rh*32 + mt*16 + lo, k = hi*8 + kk*32)
    const int aoff0 = (rh * 32 + lo) * HID + hi * 8;
    const int aoff1 = aoff0 + 16 * HID;

    // gate-stage cell mapping: 4 consecutive cells per thread
    const int brow = tid >> 2;          // batch row 0..63
    const int c0   = (tid & 3) * 4;     // col offset within 16-wide strip
    f32x4 bias4[4];
#pragma unroll
    for (int g = 0; g < 4; ++g)
        bias4[g] = *(const f32x4*)&bh[layer * H4 + 512 * g + j0 + c0];

    f32x4 creg = (f32x4)(0.f);          // cell state

    __shared__ float lds_g[4][64][16];

    for (int s = 0; s <= TSEQ; ++s) {
        // ---- stage barrier: relaxed sc1 spin; NO fence (no buffer_inv) ----
        if (s > 0) {
            if (tid < 64) {
                const int* f  = (tid < 32) ? &flagsL0[tid] : &flagsL1[tid - 32];
                const int thr = (tid < 32) ? s : (layer == 0 ? s - (DEPTH - 2) : s);
                while (__hip_atomic_load(f, __ATOMIC_RELAXED,
                                         __HIP_MEMORY_SCOPE_AGENT) < thr) { }
            }
            __syncthreads();
        }

        const int t = s - layer;
        if (t >= 0 && t < TSEQ) {
            const int pslot = (t == 0) ? ZSLOT : ((t - 1) & (DEPTH - 1));

            f32x4 acc[2][2];
#pragma unroll
            for (int mt = 0; mt < 2; ++mt)
#pragma unroll
                for (int gs = 0; gs < 2; ++gs)
                    acc[mt][gs] = (f32x4)(0.f);

            auto mfma8 = [&](bf16x8 a10, bf16x8 a11, bf16x8 a20, bf16x8 a21, int k2) {
                acc[0][0] = __builtin_amdgcn_mfma_f32_16x16x32_bf16(a10, wx[k2 + 0], acc[0][0], 0, 0, 0);
                acc[0][0] = __builtin_amdgcn_mfma_f32_16x16x32_bf16(a20, wh[k2 + 0], acc[0][0], 0, 0, 0);
                acc[0][1] = __builtin_amdgcn_mfma_f32_16x16x32_bf16(a10, wx[k2 + 1], acc[0][1], 0, 0, 0);
                acc[0][1] = __builtin_amdgcn_mfma_f32_16x16x32_bf16(a20, wh[k2 + 1], acc[0][1], 0, 0, 0);
                acc[1][0] = __builtin_amdgcn_mfma_f32_16x16x32_bf16(a11, wx[k2 + 0], acc[1][0], 0, 0, 0);
                acc[1][0] = __builtin_amdgcn_mfma_f32_16x16x32_bf16(a21, wh[k2 + 0], acc[1][0], 0, 0, 0);
                acc[1][1] = __builtin_amdgcn_mfma_f32_16x16x32_bf16(a11, wx[k2 + 1], acc[1][1], 0, 0, 0);
                acc[1][1] = __builtin_amdgcn_mfma_f32_16x16x32_bf16(a21, wh[k2 + 1], acc[1][1], 0, 0, 0);
            };

            if (layer == 0) {
                const ushort* A1 = xq  + (size_t)t * BH;        // cached (L2-hot)
                const ushort* A2 = h0r + (size_t)pslot * BH;    // coherent
#pragma unroll
                for (int kk = 0; kk < 16; ++kk) {
                    const int ko = kk * 32;
                    bf16x8 a10 = *(const bf16x8*)(A1 + aoff0 + ko);
                    bf16x8 a11 = *(const bf16x8*)(A1 + aoff1 + ko);
                    bf16x8 a20 = load_h8(A2 + aoff0 + ko);
                    bf16x8 a21 = load_h8(A2 + aoff1 + ko);
                    mfma8(a10, a11, a20, a21, kk * 2);
                }
            } else {
                const ushort* A1 = h0r + (size_t)(t & (DEPTH - 1)) * BH;  // coherent
                const ushort* A2 = h1r + (size_t)pslot * BH;              // coherent
#pragma unroll
                for (int kk = 0; kk < 16; ++kk) {
                    const int ko = kk * 32;
                    bf16x8 a10 = load_h8(A1 + aoff0 + ko);
                    bf16x8 a11 = load_h8(A1 + aoff1 + ko);
                    bf16x8 a20 = load_h8(A2 + aoff0 + ko);
                    bf16x8 a21 = load_h8(A2 + aoff1 + ko);
                    mfma8(a10, a11, a20, a21, kk * 2);
                }
            }

            // gate tiles -> LDS (C/D layout: col = lane&15, row = (lane>>4)*4 + reg)
#pragma unroll
            for (int mt = 0; mt < 2; ++mt)
#pragma unroll
                for (int gs = 0; gs < 2; ++gs)
#pragma unroll
                    for (int r = 0; r < 4; ++r)
                        lds_g[gh * 2 + gs][rh * 32 + mt * 16 + hi * 4 + r][lo] = acc[mt][gs][r];
            __syncthreads();

            // gates: each thread handles 4 consecutive cells of row brow
            f32x4 gi = *(const f32x4*)&lds_g[0][brow][c0] + bias4[0];
            f32x4 gf = *(const f32x4*)&lds_g[1][brow][c0] + bias4[1];
            f32x4 gg = *(const f32x4*)&lds_g[2][brow][c0] + bias4[2];
            f32x4 go = *(const f32x4*)&lds_g[3][brow][c0] + bias4[3];
            f32x4 cn, hn;
#pragma unroll
            for (int q = 0; q < 4; ++q) {
                float si = 1.f / (1.f + __expf(-gi[q]));
                float sf = 1.f / (1.f + __expf(-gf[q]));
                float so = 1.f / (1.f + __expf(-go[q]));
                float tg = tanhf(gg[q]);
                cn[q] = sf * creg[q] + si * tg;
                hn[q] = so * tanhf(cn[q]);
            }
            creg = cn;

            // publish h via coherent (sc1) store — no wbl2 needed
            ushort* hw = ((layer == 0) ? h0r : h1r)
                       + (size_t)(t & (DEPTH - 1)) * BH + (size_t)brow * HID + j0 + c0;
            u64 hp = (u64)f32_to_bf16(hn[0])
                   | ((u64)f32_to_bf16(hn[1]) << 16)
                   | ((u64)f32_to_bf16(hn[2]) << 32)
                   | ((u64)f32_to_bf16(hn[3]) << 48);
            __hip_atomic_store((u64*)hw, hp, __ATOMIC_RELAXED, __HIP_MEMORY_SCOPE_AGENT);

            if (layer == 1)
                *(f32x4*)&out[(size_t)t * BH + (size_t)brow * HID + j0 + c0] = hn;
            if (t == TSEQ - 1) {
                size_t base = (size_t)TSEQ * BH + (size_t)layer * BH
                            + (size_t)brow * HID + j0 + c0;
                *(f32x4*)&out[base] = hn;                       // h_fin
                *(f32x4*)&out[base + 2 * (size_t)BH] = cn;      // c_fin
            }
        }

        // ---- publish flag: drain own stores (reached MALL), then relaxed store ----
        asm volatile("s_waitcnt vmcnt(0)" ::: "memory");
        __syncthreads();
        if (tid == 0)
            __hip_atomic_store(layer ? &flagsL1[strip] : &flagsL0[strip], s + 1,
                               __ATOMIC_RELAXED, __HIP_MEMORY_SCOPE_AGENT);
    }
}

extern "C" void kernel_launch(void* const* d_in, const int* in_sizes, int n_in,
                              void* d_out, int out_size, void* d_ws, size_t ws_size,
                              hipStream_t stream) {
    const float* x  = (const float*)d_in[0];
    const float* Wh = (const float*)d_in[1];
    const float* Wx = (const float*)d_in[2];
    const float* bh = (const float*)d_in[3];
    float* out = (float*)d_out;

    char* ws = (char*)d_ws;
    // layout: WT 8MB | xq 32MB | h0r | h1r | flags   (~41.2MB total)
    ushort* WT = (ushort*)ws;
    ushort* xq = (ushort*)(ws + ((size_t)8 << 20));
    char* state = ws + ((size_t)8 << 20) + ((size_t)32 << 20);
    ushort* h0r = (ushort*)state;                          // [DEPTH+1][64][512]
    ushort* h1r = h0r + (size_t)(DEPTH + 1) * BH;
    int* flagsL0 = (int*)(h1r + (size_t)(DEPTH + 1) * BH); // [32]
    int* flagsL1 = flagsL0 + 32;
    size_t clear_bytes = (size_t)2 * (DEPTH + 1) * BH * sizeof(ushort) + 64 * sizeof(int);

    hipMemsetAsync(state, 0, clear_bytes, stream);  // zero rings + zero-slots + flags
    convert_x<<<2048, 256, 0, stream>>>(x, xq);
    transpose_w<<<1024, 256, 0, stream>>>(Wh, Wx, WT);
    lstm_persistent<<<64, 256, 0, stream>>>(WT, xq, bh, h0r, h1r, out, flagsL0, flagsL1);
}

// Round 5
// 2339.008 us; speedup vs baseline: 6.0670x; 3.6538x over previous
//
#include <hip/hip_runtime.h>
#include <hip/hip_bf16.h>

// LSTM: T=512, B=64, H=512, L=2.  inputs: x[T,B,H] f32, Wh[L,H,4H], Wx[L,H,4H], bh[L,4H]
// out = concat(out[T,B,H], h_fin[L,B,H], c_fin[L,B,H]) f32.
//
// R5: 256 persistent WGs = 2 layers x 32 col-strips x 4 row-quads, 512 thr each.
// Each WG computes a 16x64 gate tile (16 batch rows, 4 gates x 16 cols).
// Per-stage fabric volume per CU cut to 16KB/matrix (rows-quad slice of h),
// staged into LDS with 16B sc1 loads issued back-to-back (max in-flight).
// Cross-WG h via sc1 (MALL-coherent, no L2 flush); flags per (layer,quad,strip).

#define TSEQ 512
#define BATCH 64
#define HID 512
#define H4 2048
#define BH (BATCH * HID)
#define DEPTH 8
#define ZSLOT DEPTH
#define QR 16            // batch rows per quad

typedef short bf16x8 __attribute__((ext_vector_type(8)));
typedef float f32x4 __attribute__((ext_vector_type(4)));
typedef unsigned long long u64;

__device__ __forceinline__ ushort f32_to_bf16(float f) {
    unsigned u = __builtin_bit_cast(unsigned, f);
    u += 0x7FFFu + ((u >> 16) & 1u);   // round-to-nearest-even
    return (ushort)(u >> 16);
}

// 16B agent-coherent load (bypasses L1/L2, serviced at MALL)
__device__ __forceinline__ bf16x8 load16_sc1(const ushort* p) {
    bf16x8 v;
    asm volatile("global_load_dwordx4 %0, %1, off sc1" : "=v"(v) : "v"(p));
    return v;
}

// ---- convert x f32 -> bf16 (vectorized) ----
__global__ __launch_bounds__(256) void convert_x(const float* __restrict__ x,
                                                 ushort* __restrict__ xq) {
    const int n4 = (TSEQ * BATCH * HID) / 4;
    int stride = gridDim.x * blockDim.x;
    for (int i = blockIdx.x * blockDim.x + threadIdx.x; i < n4; i += stride) {
        float4 v = ((const float4*)x)[i];
        ushort4 o;
        o.x = f32_to_bf16(v.x);
        o.y = f32_to_bf16(v.y);
        o.z = f32_to_bf16(v.z);
        o.w = f32_to_bf16(v.w);
        ((ushort4*)xq)[i] = o;
    }
}

// ---- transpose+convert weights: WT[m][n][k] = W[k][n], m: 0=Wx0 1=Wh0 2=Wx1 3=Wh1 ----
__global__ __launch_bounds__(256) void transpose_w(const float* __restrict__ Wh,
                                                   const float* __restrict__ Wx,
                                                   ushort* __restrict__ WT) {
    int bid = blockIdx.x;            // 4 * 8 * 32 = 1024 blocks
    int m  = bid >> 8;               // 0..3
    int kt = (bid >> 5) & 7;         // k tile (64)
    int nt = bid & 31;               // n tile (64)
    const float* src = ((m & 1) ? Wh : Wx) + (size_t)(m >> 1) * (HID * H4);

    __shared__ float tile[64][65];
    int c  = threadIdx.x & 63;
    int r0 = (threadIdx.x >> 6) * 16;
    for (int i = 0; i < 16; ++i) {
        int r = r0 + i;
        tile[r][c] = src[(size_t)(kt * 64 + r) * H4 + nt * 64 + c];
    }
    __syncthreads();
    int k  = threadIdx.x & 63;
    int n0 = (threadIdx.x >> 6) * 16;
    for (int i = 0; i < 16; ++i) {
        int n = n0 + i;
        WT[(size_t)m * (H4 * HID) + (size_t)(nt * 64 + n) * HID + kt * 64 + k] =
            f32_to_bf16(tile[k][n]);
    }
}

// ---- persistent LSTM kernel: 256 WGs x 512 threads ----
__global__ __launch_bounds__(512, 2) void lstm_persistent(
    const ushort* __restrict__ WT,   // [4][2048][512] bf16 (N-major, K contiguous)
    const ushort* __restrict__ xq,   // [512][64][512] bf16
    const float*  __restrict__ bh,   // [2][2048]
    ushort* __restrict__ h0r,        // [DEPTH+1][64][512] bf16 ring (+ zero slot)
    ushort* __restrict__ h1r,        // [DEPTH+1][64][512]
    float*  __restrict__ out,        // d_out
    int*    __restrict__ flags)      // [2][4][32] stage counters, zeroed
{
    const int wg    = blockIdx.x;        // 0..255
    const int layer = wg >> 7;
    const int quad  = (wg >> 5) & 3;
    const int strip = wg & 31;
    const int j0    = strip * 16;
    const int tid   = threadIdx.x;
    const int wave  = tid >> 6;          // 0..7
    const int lane  = tid & 63;
    const int g     = wave & 3;          // gate
    const int kh    = wave >> 2;         // K half (0..1)
    const int lo    = lane & 15;
    const int hi    = lane >> 4;

    // pin this wave's weight fragments (8 kk x 2 matrices = 64 VGPR)
    const ushort* bx = WT + (size_t)(layer * 2 + 0) * (H4 * HID)
                     + (size_t)(g * 512 + j0 + lo) * HID + kh * 256 + hi * 8;
    const ushort* bw = WT + (size_t)(layer * 2 + 1) * (H4 * HID)
                     + (size_t)(g * 512 + j0 + lo) * HID + kh * 256 + hi * 8;
    bf16x8 wx[8], wh[8];
#pragma unroll
    for (int kk = 0; kk < 8; ++kk) {
        wx[kk] = *(const bf16x8*)(bx + kk * 32);
        wh[kk] = *(const bf16x8*)(bw + kk * 32);
    }

    // gate-phase mapping (threads 0..63 = wave 0): row grow (0..15), cols gc0..gc0+3
    const int grow = tid >> 2;
    const int gc0  = (tid & 3) * 4;
    f32x4 bias4[4];
#pragma unroll
    for (int gg = 0; gg < 4; ++gg)
        bias4[gg] = *(const f32x4*)&bh[layer * H4 + gg * 512 + j0 + gc0];
    f32x4 creg = (f32x4)(0.f);

    __shared__ __align__(16) ushort ldsA[2][QR * HID];    // 32 KB: A1, A2 tiles
    __shared__ __align__(16) float  lds_g[4][2][QR][16];  // 8 KB gate partials

    // staging: 1024 16B-chunks per matrix; this thread: chunks tid and tid+512
    const int rowa = tid >> 6,        kba = tid & 63;
    const int rowb = (tid + 512) >> 6, kbb = tid & 63;     // (tid+512)&63 == tid&63
    const int goffa = (quad * QR + rowa) * HID + kba * 8;
    const int goffb = (quad * QR + rowb) * HID + kbb * 8;
    const int laddra = ((rowa << 10) + (kba << 4)) ^ ((rowa & 7) << 4);
    const int laddrb = ((rowb << 10) + (kbb << 4)) ^ ((rowb & 7) << 4);

    int* myflag = &flags[layer * 128 + quad * 32 + strip];

    for (int s = 0; s <= TSEQ; ++s) {
        // ---- stage barrier: wave0 polls 64 flags (own-quad L0 + L1 groups) ----
        if (s > 0) {
            if (tid < 64) {
                int idx, thr;
                if (tid < 32) { idx = quad * 32 + tid;              thr = s; }
                else          { idx = 128 + quad * 32 + (tid - 32);
                                thr = (layer == 0) ? s - 6 : s; }   // ring anti-dep slack
                const int* f = &flags[idx];
                while (__hip_atomic_load(f, __ATOMIC_RELAXED,
                                         __HIP_MEMORY_SCOPE_AGENT) < thr)
                    __builtin_amdgcn_s_sleep(1);
            }
            __syncthreads();
        }

        const int t = s - layer;
        if (t >= 0 && t < TSEQ) {
            const int pslot = (t == 0) ? ZSLOT : ((t - 1) & (DEPTH - 1));
            __builtin_amdgcn_sched_barrier(0);
            bf16x8 v0, v1, v2, v3;
            if (layer == 0) {
                const ushort* A1 = xq  + (size_t)t * BH;              // L2-cached
                const ushort* A2 = h0r + (size_t)pslot * BH;          // coherent
                v0 = *(const bf16x8*)(A1 + goffa);
                v1 = *(const bf16x8*)(A1 + goffb);
                v2 = load16_sc1(A2 + goffa);
                v3 = load16_sc1(A2 + goffb);
            } else {
                const ushort* A1 = h0r + (size_t)(t & (DEPTH - 1)) * BH;  // coherent
                const ushort* A2 = h1r + (size_t)pslot * BH;              // coherent
                v0 = load16_sc1(A1 + goffa);
                v1 = load16_sc1(A1 + goffb);
                v2 = load16_sc1(A2 + goffa);
                v3 = load16_sc1(A2 + goffb);
            }
            asm volatile("s_waitcnt vmcnt(0)" ::: "memory");
            __builtin_amdgcn_sched_barrier(0);
            *(bf16x8*)((char*)&ldsA[0][0] + laddra) = v0;
            *(bf16x8*)((char*)&ldsA[0][0] + laddrb) = v1;
            *(bf16x8*)((char*)&ldsA[1][0] + laddra) = v2;
            *(bf16x8*)((char*)&ldsA[1][0] + laddrb) = v3;
            __syncthreads();

            // MFMA: wave (g, kh) computes 16x16 gate tile, K-half kh
            f32x4 acc = (f32x4)(0.f);
#pragma unroll
            for (int kk = 0; kk < 8; ++kk) {
                const int kb2 = kh * 512 + kk * 64 + hi * 16;        // byte offset in row
                const int ad  = ((lo << 10) + kb2) ^ ((lo & 7) << 4);
                bf16x8 a1 = *(const bf16x8*)((char*)&ldsA[0][0] + ad);
                bf16x8 a2 = *(const bf16x8*)((char*)&ldsA[1][0] + ad);
                acc = __builtin_amdgcn_mfma_f32_16x16x32_bf16(a1, wx[kk], acc, 0, 0, 0);
                acc = __builtin_amdgcn_mfma_f32_16x16x32_bf16(a2, wh[kk], acc, 0, 0, 0);
            }
            // C/D layout: col = lane&15 (gate col), row = (lane>>4)*4 + r (batch row)
#pragma unroll
            for (int r = 0; r < 4; ++r)
                lds_g[g][kh][hi * 4 + r][lo] = acc[r];
            __syncthreads();

            // gates (wave 0 only): 4 cells per thread
            if (tid < 64) {
                f32x4 gi = *(const f32x4*)&lds_g[0][0][grow][gc0]
                         + *(const f32x4*)&lds_g[0][1][grow][gc0] + bias4[0];
                f32x4 gf = *(const f32x4*)&lds_g[1][0][grow][gc0]
                         + *(const f32x4*)&lds_g[1][1][grow][gc0] + bias4[1];
                f32x4 gg = *(const f32x4*)&lds_g[2][0][grow][gc0]
                         + *(const f32x4*)&lds_g[2][1][grow][gc0] + bias4[2];
                f32x4 go = *(const f32x4*)&lds_g[3][0][grow][gc0]
                         + *(const f32x4*)&lds_g[3][1][grow][gc0] + bias4[3];
                f32x4 cn, hn;
#pragma unroll
                for (int q = 0; q < 4; ++q) {
                    float si = 1.f / (1.f + __expf(-gi[q]));
                    float sf = 1.f / (1.f + __expf(-gf[q]));
                    float so = 1.f / (1.f + __expf(-go[q]));
                    float tg = tanhf(gg[q]);
                    cn[q] = sf * creg[q] + si * tg;
                    hn[q] = so * tanhf(cn[q]);
                }
                creg = cn;

                // publish h (sc1), drain THIS wave's stores, then flag
                ushort* hw = ((layer == 0) ? h0r : h1r)
                           + (size_t)(t & (DEPTH - 1)) * BH
                           + (size_t)(quad * QR + grow) * HID + j0 + gc0;
                u64 hp = (u64)f32_to_bf16(hn[0])
                       | ((u64)f32_to_bf16(hn[1]) << 16)
                       | ((u64)f32_to_bf16(hn[2]) << 32)
                       | ((u64)f32_to_bf16(hn[3]) << 48);
                __hip_atomic_store((u64*)hw, hp, __ATOMIC_RELAXED,
                                   __HIP_MEMORY_SCOPE_AGENT);
                asm volatile("s_waitcnt vmcnt(0)" ::: "memory");
                if (tid == 0)
                    __hip_atomic_store(myflag, s + 1, __ATOMIC_RELAXED,
                                       __HIP_MEMORY_SCOPE_AGENT);
                // out / finals AFTER flag (off the critical path)
                if (layer == 1)
                    *(f32x4*)&out[(size_t)t * BH + (size_t)(quad * QR + grow) * HID
                                  + j0 + gc0] = hn;
                if (t == TSEQ - 1) {
                    size_t base = (size_t)TSEQ * BH + (size_t)layer * BH
                                + (size_t)(quad * QR + grow) * HID + j0 + gc0;
                    *(f32x4*)&out[base] = hn;                       // h_fin
                    *(f32x4*)&out[base + 2 * (size_t)BH] = cn;      // c_fin
                }
            }
        } else {
            // inactive stage still publishes (consumers rely on monotone flags)
            if (tid == 0)
                __hip_atomic_store(myflag, s + 1, __ATOMIC_RELAXED,
                                   __HIP_MEMORY_SCOPE_AGENT);
        }
    }
}

extern "C" void kernel_launch(void* const* d_in, const int* in_sizes, int n_in,
                              void* d_out, int out_size, void* d_ws, size_t ws_size,
                              hipStream_t stream) {
    const float* x  = (const float*)d_in[0];
    const float* Wh = (const float*)d_in[1];
    const float* Wx = (const float*)d_in[2];
    const float* bh = (const float*)d_in[3];
    float* out = (float*)d_out;

    char* ws = (char*)d_ws;
    // layout: WT 8MB | xq 32MB | h0r | h1r | flags   (~41.2MB total)
    ushort* WT = (ushort*)ws;
    ushort* xq = (ushort*)(ws + ((size_t)8 << 20));
    char* state = ws + ((size_t)8 << 20) + ((size_t)32 << 20);
    ushort* h0r = (ushort*)state;                          // [DEPTH+1][64][512]
    ushort* h1r = h0r + (size_t)(DEPTH + 1) * BH;
    int* flags  = (int*)(h1r + (size_t)(DEPTH + 1) * BH);  // [2][4][32]
    size_t clear_bytes = (size_t)2 * (DEPTH + 1) * BH * sizeof(ushort) + 256 * sizeof(int);

    hipMemsetAsync(state, 0, clear_bytes, stream);  // zero rings + zero-slots + flags
    convert_x<<<2048, 256, 0, stream>>>(x, xq);
    transpose_w<<<1024, 256, 0, stream>>>(Wh, Wx, WT);
    lstm_persistent<<<256, 512, 0, stream>>>(WT, xq, bh, h0r, h1r, out, flags);
}

// Round 6
// 2336.662 us; speedup vs baseline: 6.0731x; 1.0010x over previous
//
#include <hip/hip_runtime.h>
#include <hip/hip_bf16.h>

// LSTM: T=512, B=64, H=512, L=2.  inputs: x[T,B,H] f32, Wh[L,H,4H], Wx[L,H,4H], bh[L,4H]
// out = concat(out[T,B,H], h_fin[L,B,H], c_fin[L,B,H]) f32.
//
// R6 = R5 (256 WGs = 2 layers x 32 strips x 4 row-quads, LDS-staged sc1 h
// exchange, MALL-coherent flags) + serial-tail cuts:
//  - weights truly register-pinned (asm "+v" keep-alive; R5's VGPR=76 showed
//    the compiler sank the loads back into the loop)
//  - gate/nonlinearity phase on 2 waves (128 thr x 2 cells) instead of 1
//  - lds_g padded [16][18] (R5: 4-way bank conflict on every acc write)
//  - xq prefetch issued BEFORE the flag poll (static data, hides poll latency)
//  - pure spin (no s_sleep) for minimum observe latency

#define TSEQ 512
#define BATCH 64
#define HID 512
#define H4 2048
#define BH (BATCH * HID)
#define DEPTH 8
#define ZSLOT DEPTH
#define QR 16            // batch rows per quad

typedef short bf16x8 __attribute__((ext_vector_type(8)));
typedef float f32x4 __attribute__((ext_vector_type(4)));
typedef float f32x2 __attribute__((ext_vector_type(2)));
typedef unsigned long long u64;

__device__ __forceinline__ ushort f32_to_bf16(float f) {
    unsigned u = __builtin_bit_cast(unsigned, f);
    u += 0x7FFFu + ((u >> 16) & 1u);   // round-to-nearest-even
    return (ushort)(u >> 16);
}

// 16B agent-coherent load (bypasses L1/L2, serviced at MALL)
__device__ __forceinline__ bf16x8 load16_sc1(const ushort* p) {
    bf16x8 v;
    asm volatile("global_load_dwordx4 %0, %1, off sc1" : "=v"(v) : "v"(p));
    return v;
}

// ---- convert x f32 -> bf16 (vectorized) ----
__global__ __launch_bounds__(256) void convert_x(const float* __restrict__ x,
                                                 ushort* __restrict__ xq) {
    const int n4 = (TSEQ * BATCH * HID) / 4;
    int stride = gridDim.x * blockDim.x;
    for (int i = blockIdx.x * blockDim.x + threadIdx.x; i < n4; i += stride) {
        float4 v = ((const float4*)x)[i];
        ushort4 o;
        o.x = f32_to_bf16(v.x);
        o.y = f32_to_bf16(v.y);
        o.z = f32_to_bf16(v.z);
        o.w = f32_to_bf16(v.w);
        ((ushort4*)xq)[i] = o;
    }
}

// ---- transpose+convert weights: WT[m][n][k] = W[k][n], m: 0=Wx0 1=Wh0 2=Wx1 3=Wh1 ----
__global__ __launch_bounds__(256) void transpose_w(const float* __restrict__ Wh,
                                                   const float* __restrict__ Wx,
                                                   ushort* __restrict__ WT) {
    int bid = blockIdx.x;            // 4 * 8 * 32 = 1024 blocks
    int m  = bid >> 8;               // 0..3
    int kt = (bid >> 5) & 7;         // k tile (64)
    int nt = bid & 31;               // n tile (64)
    const float* src = ((m & 1) ? Wh : Wx) + (size_t)(m >> 1) * (HID * H4);

    __shared__ float tile[64][65];
    int c  = threadIdx.x & 63;
    int r0 = (threadIdx.x >> 6) * 16;
    for (int i = 0; i < 16; ++i) {
        int r = r0 + i;
        tile[r][c] = src[(size_t)(kt * 64 + r) * H4 + nt * 64 + c];
    }
    __syncthreads();
    int k  = threadIdx.x & 63;
    int n0 = (threadIdx.x >> 6) * 16;
    for (int i = 0; i < 16; ++i) {
        int n = n0 + i;
        WT[(size_t)m * (H4 * HID) + (size_t)(nt * 64 + n) * HID + kt * 64 + k] =
            f32_to_bf16(tile[k][n]);
    }
}

// ---- persistent LSTM kernel: 256 WGs x 512 threads ----
__global__ __launch_bounds__(512, 2) void lstm_persistent(
    const ushort* __restrict__ WT,   // [4][2048][512] bf16 (N-major, K contiguous)
    const ushort* __restrict__ xq,   // [512][64][512] bf16
    const float*  __restrict__ bh,   // [2][2048]
    ushort* __restrict__ h0r,        // [DEPTH+1][64][512] bf16 ring (+ zero slot)
    ushort* __restrict__ h1r,        // [DEPTH+1][64][512]
    float*  __restrict__ out,        // d_out
    int*    __restrict__ flags)      // [2][4][32] stage counters, zeroed
{
    const int wg    = blockIdx.x;        // 0..255
    const int layer = wg >> 7;
    const int quad  = (wg >> 5) & 3;
    const int strip = wg & 31;
    const int j0    = strip * 16;
    const int tid   = threadIdx.x;
    const int wave  = tid >> 6;          // 0..7
    const int lane  = tid & 63;
    const int g     = wave & 3;          // gate
    const int kh    = wave >> 2;         // K half (0..1)
    const int lo    = lane & 15;
    const int hi    = lane >> 4;

    // pin this wave's weight fragments (8 kk x 2 matrices = 64 VGPR), and keep
    // them pinned: the asm "+v" makes each frag an opaque register value the
    // compiler cannot rematerialize-by-reload inside the loop (R5 regression).
    const ushort* bx = WT + (size_t)(layer * 2 + 0) * (H4 * HID)
                     + (size_t)(g * 512 + j0 + lo) * HID + kh * 256 + hi * 8;
    const ushort* bw = WT + (size_t)(layer * 2 + 1) * (H4 * HID)
                     + (size_t)(g * 512 + j0 + lo) * HID + kh * 256 + hi * 8;
    bf16x8 wx[8], wh[8];
#pragma unroll
    for (int kk = 0; kk < 8; ++kk) {
        wx[kk] = *(const bf16x8*)(bx + kk * 32);
        wh[kk] = *(const bf16x8*)(bw + kk * 32);
    }
#pragma unroll
    for (int kk = 0; kk < 8; ++kk) {
        asm volatile("" : "+v"(wx[kk]));
        asm volatile("" : "+v"(wh[kk]));
    }

    // gate-phase mapping (threads 0..127): row = tid>>3 (0..15), cols cp,cp+1
    const int grow = tid >> 3;
    const int cp   = (tid & 7) * 2;
    f32x2 bias2[4];
#pragma unroll
    for (int gg = 0; gg < 4; ++gg)
        bias2[gg] = *(const f32x2*)&bh[layer * H4 + gg * 512 + j0 + cp];
    f32x2 creg = (f32x2)(0.f);

    __shared__ __align__(16) ushort ldsA[2][QR * HID];     // 32 KB: A1, A2 tiles
    __shared__ __align__(16) float  lds_g[4][2][QR][18];   // padded: no 4-way conflict

    // staging: 1024 16B-chunks per matrix; this thread: chunks tid and tid+512
    const int rowa = tid >> 6;             // 0..7
    const int rowb = rowa + 8;             // 8..15
    const int kba  = tid & 63;
    const int goffa = (quad * QR + rowa) * HID + kba * 8;
    const int goffb = (quad * QR + rowb) * HID + kba * 8;
    const int laddra = ((rowa << 10) + (kba << 4)) ^ ((rowa & 7) << 4);
    const int laddrb = ((rowb << 10) + (kba << 4)) ^ ((rowb & 7) << 4);

    int* myflag = &flags[layer * 128 + quad * 32 + strip];

    for (int s = 0; s <= TSEQ; ++s) {
        const int t = s - layer;
        const bool active = (t >= 0 && t < TSEQ);

        bf16x8 v0, v1, v2, v3;
        // xq is static: issue its loads BEFORE the poll (overlaps observe latency)
        if (active && layer == 0) {
            const ushort* A1 = xq + (size_t)t * BH;
            v0 = *(const bf16x8*)(A1 + goffa);
            v1 = *(const bf16x8*)(A1 + goffb);
        }

        // ---- stage barrier: wave0 polls 64 flags (own-quad groups), pure spin ----
        if (s > 0) {
            if (tid < 64) {
                int idx, thr;
                if (tid < 32) { idx = quad * 32 + tid;              thr = s; }
                else          { idx = 128 + quad * 32 + (tid - 32);
                                thr = (layer == 0) ? s - (DEPTH - 2) : s; }
                const int* f = &flags[idx];
                while (__hip_atomic_load(f, __ATOMIC_RELAXED,
                                         __HIP_MEMORY_SCOPE_AGENT) < thr) { }
            }
            __syncthreads();
        }

        if (active) {
            const int pslot = (t == 0) ? ZSLOT : ((t - 1) & (DEPTH - 1));
            if (layer == 0) {
                const ushort* A2 = h0r + (size_t)pslot * BH;              // coherent
                v2 = load16_sc1(A2 + goffa);
                v3 = load16_sc1(A2 + goffb);
            } else {
                const ushort* A1 = h0r + (size_t)(t & (DEPTH - 1)) * BH;  // coherent
                const ushort* A2 = h1r + (size_t)pslot * BH;              // coherent
                v0 = load16_sc1(A1 + goffa);
                v1 = load16_sc1(A1 + goffb);
                v2 = load16_sc1(A2 + goffa);
                v3 = load16_sc1(A2 + goffb);
            }
            asm volatile("s_waitcnt vmcnt(0)" ::: "memory");
            __builtin_amdgcn_sched_barrier(0);
            *(bf16x8*)((char*)&ldsA[0][0] + laddra) = v0;
            *(bf16x8*)((char*)&ldsA[0][0] + laddrb) = v1;
            *(bf16x8*)((char*)&ldsA[1][0] + laddra) = v2;
            *(bf16x8*)((char*)&ldsA[1][0] + laddrb) = v3;
            __syncthreads();

            // MFMA: wave (g, kh) computes 16x16 gate tile, K-half kh
            f32x4 acc = (f32x4)(0.f);
#pragma unroll
            for (int kk = 0; kk < 8; ++kk) {
                const int kb2 = kh * 512 + kk * 64 + hi * 16;        // byte offset in row
                const int ad  = ((lo << 10) + kb2) ^ ((lo & 7) << 4);
                bf16x8 a1 = *(const bf16x8*)((char*)&ldsA[0][0] + ad);
                bf16x8 a2 = *(const bf16x8*)((char*)&ldsA[1][0] + ad);
                acc = __builtin_amdgcn_mfma_f32_16x16x32_bf16(a1, wx[kk], acc, 0, 0, 0);
                acc = __builtin_amdgcn_mfma_f32_16x16x32_bf16(a2, wh[kk], acc, 0, 0, 0);
            }
            // C/D layout: col = lane&15 (gate col), row = (lane>>4)*4 + r (batch row)
#pragma unroll
            for (int r = 0; r < 4; ++r)
                lds_g[g][kh][hi * 4 + r][lo] = acc[r];
            __syncthreads();

            // gates (2 waves): 2 cells per thread
            f32x2 cn, hn;
            if (tid < 128) {
                f32x2 gi = *(const f32x2*)&lds_g[0][0][grow][cp]
                         + *(const f32x2*)&lds_g[0][1][grow][cp] + bias2[0];
                f32x2 gf = *(const f32x2*)&lds_g[1][0][grow][cp]
                         + *(const f32x2*)&lds_g[1][1][grow][cp] + bias2[1];
                f32x2 gg = *(const f32x2*)&lds_g[2][0][grow][cp]
                         + *(const f32x2*)&lds_g[2][1][grow][cp] + bias2[2];
                f32x2 go = *(const f32x2*)&lds_g[3][0][grow][cp]
                         + *(const f32x2*)&lds_g[3][1][grow][cp] + bias2[3];
#pragma unroll
                for (int q = 0; q < 2; ++q) {
                    float si = 1.f / (1.f + __expf(-gi[q]));
                    float sf = 1.f / (1.f + __expf(-gf[q]));
                    float so = 1.f / (1.f + __expf(-go[q]));
                    float tg = tanhf(gg[q]);
                    cn[q] = sf * creg[q] + si * tg;
                    hn[q] = so * tanhf(cn[q]);
                }
                creg = cn;

                // publish h (sc1, 2 bf16 packed), drain this wave's stores
                ushort* hw = ((layer == 0) ? h0r : h1r)
                           + (size_t)(t & (DEPTH - 1)) * BH
                           + (size_t)(quad * QR + grow) * HID + j0 + cp;
                unsigned hp = (unsigned)f32_to_bf16(hn[0])
                            | ((unsigned)f32_to_bf16(hn[1]) << 16);
                __hip_atomic_store((unsigned*)hw, hp, __ATOMIC_RELAXED,
                                   __HIP_MEMORY_SCOPE_AGENT);
                asm volatile("s_waitcnt vmcnt(0)" ::: "memory");
            }
            __syncthreads();          // gate waves drained -> flag is safe
            if (tid == 0)
                __hip_atomic_store(myflag, s + 1, __ATOMIC_RELAXED,
                                   __HIP_MEMORY_SCOPE_AGENT);
            // out / finals AFTER the flag (off the critical path)
            if (tid < 128) {
                if (layer == 1)
                    *(f32x2*)&out[(size_t)t * BH + (size_t)(quad * QR + grow) * HID
                                  + j0 + cp] = hn;
                if (t == TSEQ - 1) {
                    size_t base = (size_t)TSEQ * BH + (size_t)layer * BH
                                + (size_t)(quad * QR + grow) * HID + j0 + cp;
                    *(f32x2*)&out[base] = hn;                       // h_fin
                    *(f32x2*)&out[base + 2 * (size_t)BH] = cn;      // c_fin
                }
            }
        } else {
            // inactive stage still publishes (consumers rely on monotone flags)
            if (tid == 0)
                __hip_atomic_store(myflag, s + 1, __ATOMIC_RELAXED,
                                   __HIP_MEMORY_SCOPE_AGENT);
        }
    }
}

extern "C" void kernel_launch(void* const* d_in, const int* in_sizes, int n_in,
                              void* d_out, int out_size, void* d_ws, size_t ws_size,
                              hipStream_t stream) {
    const float* x  = (const float*)d_in[0];
    const float* Wh = (const float*)d_in[1];
    const float* Wx = (const float*)d_in[2];
    const float* bh = (const float*)d_in[3];
    float* out = (float*)d_out;

    char* ws = (char*)d_ws;
    // layout: WT 8MB | xq 32MB | h0r | h1r | flags   (~41.2MB total)
    ushort* WT = (ushort*)ws;
    ushort* xq = (ushort*)(ws + ((size_t)8 << 20));
    char* state = ws + ((size_t)8 << 20) + ((size_t)32 << 20);
    ushort* h0r = (ushort*)state;                          // [DEPTH+1][64][512]
    ushort* h1r = h0r + (size_t)(DEPTH + 1) * BH;
    int* flags  = (int*)(h1r + (size_t)(DEPTH + 1) * BH);  // [2][4][32]
    size_t clear_bytes = (size_t)2 * (DEPTH + 1) * BH * sizeof(ushort) + 256 * sizeof(int);

    hipMemsetAsync(state, 0, clear_bytes, stream);  // zero rings + zero-slots + flags
    convert_x<<<2048, 256, 0, stream>>>(x, xq);
    transpose_w<<<1024, 256, 0, stream>>>(Wh, Wx, WT);
    lstm_persistent<<<256, 512, 0, stream>>>(WT, xq, bh, h0r, h1r, out, flags);
}